// Round 4
// baseline (56.444 us; speedup 1.0000x reference)
//
#include <hip/hip_runtime.h>

#define NP   4096      // P = 64*64 pixels per image
#define NIMG 8
#define NK   21
#define ROWH 32        // halves per packed row (64 B)
#define ITEMS_PER_IMG 544
#define CRF_BLOCKS (NIMG * ITEMS_PER_IMG / 4)   // 1088

// sqrt(0.5 * log2(e)): pre-scale features so exponent = -sum((fi-fj)^2), w = exp2(exponent)
#define FEAT_SCALE 0.84932180028801907f

typedef _Float16 half8 __attribute__((ext_vector_type(8)));
typedef float f32x4 __attribute__((ext_vector_type(4)));

__device__ __forceinline__ unsigned short h2u(_Float16 h) {
  union { _Float16 f; unsigned short u; } c; c.f = h; return c.u;
}
__device__ __forceinline__ unsigned int pk2(_Float16 a, _Float16 b) {
  return (unsigned)h2u(a) | ((unsigned)h2u(b) << 16);
}
__device__ __forceinline__ unsigned long long pk4(_Float16 a, _Float16 b, _Float16 c, _Float16 d) {
  return (unsigned long long)pk2(a, b) | ((unsigned long long)pk2(c, d) << 32);
}

__device__ __forceinline__ void resize_w(int o, float* w, int* t) {
  // jax.image.resize bilinear antialias=True, 128->64 (verified exact rounds 1-3)
  const float ww[4] = {0.25f, 0.75f, 0.75f, 0.25f};
  float s = 0.f;
  #pragma unroll
  for (int a = 0; a < 4; ++a) {
    int tap = 2 * o - 1 + a;
    bool v = (tap >= 0) && (tap < 128);
    w[a] = v ? ww[a] : 0.f;
    t[a] = v ? tap : 0;
    s += w[a];
  }
  float inv = 1.f / s;
  #pragma unroll
  for (int a = 0; a < 4; ++a) w[a] *= inv;
}

// 384 blocks = (n, oyg, kq): kq splits the 21 seg channels into 3 groups of 7.
__global__ void __launch_bounds__(256) prep_kernel(const float* __restrict__ images,
                                                   const float* __restrict__ segs,
                                                   _Float16* __restrict__ distA,
                                                   _Float16* __restrict__ distB,
                                                   _Float16* __restrict__ segh,
                                                   double* __restrict__ acc,
                                                   unsigned* __restrict__ ctr) {
  int bid = blockIdx.x;
  if (bid == 0 && threadIdx.x == 0) { acc[0] = 0.0; ctr[0] = 0u; }
  int n = bid / 48;
  int r48 = bid % 48;
  int oyg = r48 / 3, kq = r48 % 3;
  int ox = threadIdx.x & 63, oyl = threadIdx.x >> 6;
  int oy = oyg * 4 + oyl;
  int p = oy * 64 + ox;
  int idx = n * NP + p;

  if (kq == 0) {
    // ---- bilateral features -> distA/distB rows (identical math to rounds 2-3) ----
    const float cxy  = FEAT_SCALE / 50.0f;   // sigma_xy * scale = 50
    const float crgb = FEAT_SCALE / 15.0f;   // sigma_rgb = 15
    const float* img = images + (size_t)n * 3 * NP;
    float f[5];
    f[0] = (float)ox * cxy;
    f[1] = (float)oy * cxy;
    f[2] = img[0 * NP + p] * crgb;
    f[3] = img[1 * NP + p] * crgb;
    f[4] = img[2 * NP + p] * crgb;

    _Float16 ah[5], al[5];
    float n2 = 0.f;
    #pragma unroll
    for (int d = 0; d < 5; ++d) {
      ah[d] = (_Float16)f[d];
      float rem = f[d] - (float)ah[d];
      al[d] = (_Float16)rem;
      float at = (float)ah[d] + (float)al[d];
      n2 = fmaf(at, at, n2);
    }
    _Float16 nh = (_Float16)n2;
    _Float16 nl = (_Float16)(n2 - (float)nh);

    _Float16 rowA[ROWH], rowB[ROWH];
    #pragma unroll
    for (int q = 0; q < ROWH; ++q) { rowA[q] = (_Float16)0.f; rowB[q] = (_Float16)0.f; }
    #pragma unroll
    for (int d = 0; d < 5; ++d) {
      rowA[d]      = ah[d];
      rowA[5 + d]  = al[d];
      rowA[10 + d] = ah[d];
      rowB[d]      = (_Float16)2.f * ah[d];
      rowB[5 + d]  = (_Float16)2.f * ah[d];
      rowB[10 + d] = (_Float16)2.f * al[d];
    }
    rowA[15] = nh;  rowA[16] = nl;  rowA[17] = (_Float16)1.f; rowA[18] = (_Float16)1.f;
    rowB[15] = (_Float16)-1.f; rowB[16] = (_Float16)-1.f; rowB[17] = -nh; rowB[18] = -nl;

    half8* oA = (half8*)(distA + (size_t)idx * ROWH);
    half8* oB = (half8*)(distB + (size_t)idx * ROWH);
    #pragma unroll
    for (int q = 0; q < 4; ++q) {
      oA[q] = ((half8*)rowA)[q];
      oB[q] = ((half8*)rowB)[q];
    }
  }

  // ---- seg resize for 7 channels via LDS slab ----
  __shared__ float slab[10][128];
  int r0 = 8 * oyg - 1;
  float wy[4], wx[4]; int ty[4], tx[4];
  resize_w(oy, wy, ty);                    // ty unused: rel row = 2*oyl+ay
  resize_w(ox, wx, tx);

  float outk[7];
  const float* sb = segs + (size_t)n * NK * 128 * 128;
  #pragma unroll 1
  for (int kk = 0; kk < 7; ++kk) {
    int k = kq * 7 + kk;
    __syncthreads();                       // previous slab reads done
    const float* sk = sb + (size_t)k * 128 * 128;
    #pragma unroll
    for (int q = 0; q < 5; ++q) {          // 1280 floats, coalesced
      int e = threadIdx.x + q * 256;
      int rr = e >> 7, cc = e & 127;
      int row = r0 + rr;
      row = row < 0 ? 0 : (row > 127 ? 127 : row);  // clamp; invalid taps weight 0
      slab[rr][cc] = sk[row * 128 + cc];
    }
    __syncthreads();
    float a = 0.f;
    #pragma unroll
    for (int ay = 0; ay < 4; ++ay) {
      int rel = 2 * oyl + ay;
      float rsum = 0.f;
      #pragma unroll
      for (int ax = 0; ax < 4; ++ax) rsum = fmaf(wx[ax], slab[rel][tx[ax]], rsum);
      a = fmaf(wy[ay], rsum, a);
    }
    outk[kk] = a;
  }

  _Float16 hv[7];
  #pragma unroll
  for (int kk = 0; kk < 7; ++kk) hv[kk] = (_Float16)outk[kk];
  char* rowp = (char*)(segh + (size_t)idx * ROWH);
  const _Float16 hz = (_Float16)0.f;
  if (kq == 0) {         // halves 0..6 -> bytes 0..13
    *(unsigned long long*)(rowp + 0)  = pk4(hv[0], hv[1], hv[2], hv[3]);
    *(unsigned int*)      (rowp + 8)  = pk2(hv[4], hv[5]);
    *(unsigned short*)    (rowp + 12) = h2u(hv[6]);
  } else if (kq == 1) {  // halves 7..13 -> bytes 14..27
    *(unsigned short*)    (rowp + 14) = h2u(hv[0]);
    *(unsigned long long*)(rowp + 16) = pk4(hv[1], hv[2], hv[3], hv[4]);
    *(unsigned int*)      (rowp + 24) = pk2(hv[5], hv[6]);
  } else {               // halves 14..20 + zero pad 21..31 -> bytes 28..63
    *(unsigned int*)      (rowp + 28) = pk2(hv[0], hv[1]);
    *(unsigned long long*)(rowp + 32) = pk4(hv[2], hv[3], hv[4], hv[5]);
    *(unsigned long long*)(rowp + 40) = pk4(hv[6], hz, hz, hz);
    *(unsigned long long*)(rowp + 48) = 0ull;
    *(unsigned long long*)(rowp + 56) = 0ull;
  }
}

// Triangular tile sweep; 4 i-tiles x 16 j-tiles per wave; per-m accumulators;
// explicit B prefetch; last-block writes the final output.
__global__ void __launch_bounds__(256) crf_mfma(const _Float16* __restrict__ distA,
                                                const _Float16* __restrict__ distB,
                                                const _Float16* __restrict__ segh,
                                                double* __restrict__ acc,
                                                unsigned* __restrict__ ctr,
                                                float* __restrict__ out) {
  int lane = threadIdx.x & 63, wid = threadIdx.x >> 6;
  int item = blockIdx.x * 4 + wid;         // 0..4351
  int n = item / ITEMS_PER_IMG;
  int rem = item - n * ITEMS_PER_IMG;
  int g = 0;
  for (;;) { int cnt = 4 * (16 - g); if (rem < cnt) break; rem -= cnt; ++g; }
  int span = 16 - g;
  int ist = 4 * g + rem / span;            // i-supertile (4 tiles = 64 rows)
  int c   = g + rem % span;                // j-chunk (16 tiles = 256 rows)

  int r = lane & 15, g4 = lane >> 4;
  const _Float16* dA = distA + (size_t)n * NP * ROWH;
  const _Float16* dB = distB + (size_t)n * NP * ROWH;
  const _Float16* sg = segh  + (size_t)n * NP * ROWH;

  half8 Ad[4], As[4];
  #pragma unroll
  for (int m = 0; m < 4; ++m) {
    size_t aoff = (size_t)((ist * 4 + m) * 16 + r) * ROWH + g4 * 8;
    Ad[m] = *(const half8*)(dA + aoff);
    As[m] = *(const half8*)(sg + aoff);
  }

  size_t boff = (size_t)(c * 256 + r) * ROWH + g4 * 8;
  const _Float16* pBd = dB + boff;
  const _Float16* pBs = sg + boff;

  f32x4 zero = {0.f, 0.f, 0.f, 0.f};
  float sm0 = 0.f, sm1 = 0.f, sm2 = 0.f, sm3 = 0.f;
  float sum;

  if (c > g) {                             // pure off-diagonal chunk: weight 2
    half8 Bd = *(const half8*)pBd;
    half8 Bs = *(const half8*)pBs;
    #pragma unroll 4
    for (int jt = 0; jt < 16; ++jt) {
      const _Float16* nd = (jt < 15) ? (pBd + 16 * ROWH) : pBd;
      const _Float16* ns = (jt < 15) ? (pBs + 16 * ROWH) : pBs;
      half8 nBd = *(const half8*)nd;       // prefetch next j-tile
      half8 nBs = *(const half8*)ns;
      pBd = nd; pBs = ns;
      #pragma unroll
      for (int m = 0; m < 4; ++m) {
        f32x4 ad  = __builtin_amdgcn_mfma_f32_16x16x32_f16(Ad[m], Bd, zero, 0, 0, 0);
        f32x4 as_ = __builtin_amdgcn_mfma_f32_16x16x32_f16(As[m], Bs, zero, 0, 0, 0);
        float t0 = fmaf(__builtin_amdgcn_exp2f(ad[0]), as_[0],
                   fmaf(__builtin_amdgcn_exp2f(ad[1]), as_[1], 0.f));
        float t1 = fmaf(__builtin_amdgcn_exp2f(ad[2]), as_[2],
                   fmaf(__builtin_amdgcn_exp2f(ad[3]), as_[3], 0.f));
        float t = t0 + t1;
        if (m == 0) sm0 += t; else if (m == 1) sm1 += t;
        else if (m == 2) sm2 += t; else sm3 += t;
      }
      Bd = nBd; Bs = nBs;
    }
    sum = 2.f * (sm0 + sm1 + sm2 + sm3);
  } else {                                 // diagonal chunk: per-tile weight {0,1,2}
    half8 Bd = *(const half8*)pBd;
    half8 Bs = *(const half8*)pBs;
    #pragma unroll 2
    for (int jt = 0; jt < 16; ++jt) {
      int jta = c * 16 + jt;
      const _Float16* nd = (jt < 15) ? (pBd + 16 * ROWH) : pBd;
      const _Float16* ns = (jt < 15) ? (pBs + 16 * ROWH) : pBs;
      half8 nBd = *(const half8*)nd;
      half8 nBs = *(const half8*)ns;
      pBd = nd; pBs = ns;
      #pragma unroll
      for (int m = 0; m < 4; ++m) {
        int it = ist * 4 + m;
        if (jta >= it) {                   // wave-uniform; skip zero-weight tiles
          float s = (jta > it) ? 2.f : 1.f;
          f32x4 ad  = __builtin_amdgcn_mfma_f32_16x16x32_f16(Ad[m], Bd, zero, 0, 0, 0);
          f32x4 as_ = __builtin_amdgcn_mfma_f32_16x16x32_f16(As[m], Bs, zero, 0, 0, 0);
          float t0 = fmaf(__builtin_amdgcn_exp2f(ad[0]), as_[0],
                     fmaf(__builtin_amdgcn_exp2f(ad[1]), as_[1], 0.f));
          float t1 = fmaf(__builtin_amdgcn_exp2f(ad[2]), as_[2],
                     fmaf(__builtin_amdgcn_exp2f(ad[3]), as_[3], 0.f));
          float t = s * (t0 + t1);
          if (m == 0) sm0 += t; else if (m == 1) sm1 += t;
          else if (m == 2) sm2 += t; else sm3 += t;
        }
      }
      Bd = nBd; Bs = nBs;
    }
    sum = sm0 + sm1 + sm2 + sm3;
  }

  // block reduction, then device accumulate; last block writes out
  #pragma unroll
  for (int off = 32; off > 0; off >>= 1) sum += __shfl_down(sum, off);
  __shared__ float red[4];
  if (lane == 0) red[wid] = sum;
  __syncthreads();
  if (threadIdx.x == 0) {
    float b = red[0] + red[1] + red[2] + red[3];
    atomicAdd(acc, (double)b);
    __threadfence();
    unsigned old = atomicAdd(ctr, 1u);
    if (old == (unsigned)(gridDim.x - 1)) {
      __threadfence();
      double s = *(volatile double*)acc;
      out[0] = (float)(s * (-1e-8 / 8.0));  // WEIGHT * (-sum/N)
    }
  }
}

extern "C" void kernel_launch(void* const* d_in, const int* in_sizes, int n_in,
                              void* d_out, int out_size, void* d_ws, size_t ws_size,
                              hipStream_t stream) {
  const float* images = (const float*)d_in[0];   // [8,3,64,64]
  const float* segs   = (const float*)d_in[1];   // [8,21,128,128]
  float* out  = (float*)d_out;
  double* acc = (double*)d_ws;
  unsigned* ctr = (unsigned*)((char*)d_ws + 8);
  _Float16* distA = (_Float16*)((char*)d_ws + 256);              // 2 MB
  _Float16* distB = distA + (size_t)NIMG * NP * ROWH;            // 2 MB
  _Float16* segh  = distB + (size_t)NIMG * NP * ROWH;            // 2 MB

  hipLaunchKernelGGL(prep_kernel, dim3(NIMG * 16 * 3), dim3(256), 0, stream,
                     images, segs, distA, distB, segh, acc, ctr);
  hipLaunchKernelGGL(crf_mfma, dim3(CRF_BLOCKS), dim3(256), 0, stream,
                     distA, distB, segh, acc, ctr, out);
}

// Round 5
// 50.142 us; speedup vs baseline: 1.1257x; 1.1257x over previous
//
#include <hip/hip_runtime.h>

#define NP   4096      // P = 64*64 pixels per image
#define NIMG 8
#define NK   21
#define ROWH 32        // halves per packed row (64 B)
#define NT   16        // 256-row supertiles per image
#define ITEMS_PER_IMG 136               // triangular (I,J) supertile pairs, J>=I
#define CRF_BLOCKS (NIMG * ITEMS_PER_IMG)   // 1088

// sqrt(0.5 * log2(e)): pre-scale features so exponent = -sum((fi-fj)^2), w = exp2(exponent)
#define FEAT_SCALE 0.84932180028801907f

typedef _Float16 half8 __attribute__((ext_vector_type(8)));
typedef float f32x4 __attribute__((ext_vector_type(4)));

__device__ __forceinline__ unsigned short h2u(_Float16 h) {
  union { _Float16 f; unsigned short u; } c; c.f = h; return c.u;
}
__device__ __forceinline__ unsigned int pk2(_Float16 a, _Float16 b) {
  return (unsigned)h2u(a) | ((unsigned)h2u(b) << 16);
}
__device__ __forceinline__ unsigned long long pk4(_Float16 a, _Float16 b, _Float16 c, _Float16 d) {
  return (unsigned long long)pk2(a, b) | ((unsigned long long)pk2(c, d) << 32);
}

__device__ __forceinline__ void resize_w(int o, float* w, int* t) {
  // jax.image.resize bilinear antialias=True, 128->64 (verified exact rounds 1-4)
  const float ww[4] = {0.25f, 0.75f, 0.75f, 0.25f};
  float s = 0.f;
  #pragma unroll
  for (int a = 0; a < 4; ++a) {
    int tap = 2 * o - 1 + a;
    bool v = (tap >= 0) && (tap < 128);
    w[a] = v ? ww[a] : 0.f;
    t[a] = v ? tap : 0;
    s += w[a];
  }
  float inv = 1.f / s;
  #pragma unroll
  for (int a = 0; a < 4; ++a) w[a] *= inv;
}

// 384 blocks = (n, oyg, kq): kq splits the 21 seg channels into 3 groups of 7.
// Seg slab double-buffered: next channel's loads issued before current compute.
__global__ void __launch_bounds__(256) prep_kernel(const float* __restrict__ images,
                                                   const float* __restrict__ segs,
                                                   _Float16* __restrict__ distA,
                                                   _Float16* __restrict__ distB,
                                                   _Float16* __restrict__ segh,
                                                   double* __restrict__ acc,
                                                   unsigned* __restrict__ ctr) {
  int bid = blockIdx.x;
  if (bid == 0 && threadIdx.x == 0) { acc[0] = 0.0; ctr[0] = 0u; }
  int n = bid / 48;
  int r48 = bid % 48;
  int oyg = r48 / 3, kq = r48 % 3;
  int tid = threadIdx.x;
  int ox = tid & 63, oyl = tid >> 6;
  int oy = oyg * 4 + oyl;
  int p = oy * 64 + ox;
  int idx = n * NP + p;

  if (kq == 0) {
    // ---- bilateral features -> distA/distB rows (identical math to rounds 2-4) ----
    const float cxy  = FEAT_SCALE / 50.0f;   // sigma_xy * scale = 50
    const float crgb = FEAT_SCALE / 15.0f;   // sigma_rgb = 15
    const float* img = images + (size_t)n * 3 * NP;
    float f[5];
    f[0] = (float)ox * cxy;
    f[1] = (float)oy * cxy;
    f[2] = img[0 * NP + p] * crgb;
    f[3] = img[1 * NP + p] * crgb;
    f[4] = img[2 * NP + p] * crgb;

    _Float16 ah[5], al[5];
    float n2 = 0.f;
    #pragma unroll
    for (int d = 0; d < 5; ++d) {
      ah[d] = (_Float16)f[d];
      float rem = f[d] - (float)ah[d];
      al[d] = (_Float16)rem;
      float at = (float)ah[d] + (float)al[d];
      n2 = fmaf(at, at, n2);
    }
    _Float16 nh = (_Float16)n2;
    _Float16 nl = (_Float16)(n2 - (float)nh);

    _Float16 rowA[ROWH], rowB[ROWH];
    #pragma unroll
    for (int q = 0; q < ROWH; ++q) { rowA[q] = (_Float16)0.f; rowB[q] = (_Float16)0.f; }
    #pragma unroll
    for (int d = 0; d < 5; ++d) {
      rowA[d]      = ah[d];
      rowA[5 + d]  = al[d];
      rowA[10 + d] = ah[d];
      rowB[d]      = (_Float16)2.f * ah[d];
      rowB[5 + d]  = (_Float16)2.f * ah[d];
      rowB[10 + d] = (_Float16)2.f * al[d];
    }
    rowA[15] = nh;  rowA[16] = nl;  rowA[17] = (_Float16)1.f; rowA[18] = (_Float16)1.f;
    rowB[15] = (_Float16)-1.f; rowB[16] = (_Float16)-1.f; rowB[17] = -nh; rowB[18] = -nl;

    half8* oA = (half8*)(distA + (size_t)idx * ROWH);
    half8* oB = (half8*)(distB + (size_t)idx * ROWH);
    #pragma unroll
    for (int q = 0; q < 4; ++q) {
      oA[q] = ((half8*)rowA)[q];
      oB[q] = ((half8*)rowB)[q];
    }
  }

  // ---- seg resize for 7 channels, double-buffered LDS slab ----
  __shared__ float slab[2][10][128];
  int r0 = 8 * oyg - 1;
  float wy[4], wx[4]; int ty[4], tx[4];
  resize_w(oy, wy, ty);                    // ty unused: rel row = 2*oyl+ay
  resize_w(ox, wx, tx);

  // per-thread slab-load descriptors (5 elements each)
  int lofs[5], lrr[5], lcc[5];
  #pragma unroll
  for (int q = 0; q < 5; ++q) {
    int e = tid + q * 256;
    int rr = e >> 7, cc = e & 127;
    int row = r0 + rr;
    row = row < 0 ? 0 : (row > 127 ? 127 : row);   // clamp; invalid taps weight 0
    lofs[q] = row * 128 + cc;
    lrr[q] = rr; lcc[q] = cc;
  }

  const float* sb = segs + (size_t)n * NK * 128 * 128;
  float rg[5];
  {
    const float* sk = sb + (size_t)(kq * 7) * 128 * 128;
    #pragma unroll
    for (int q = 0; q < 5; ++q) rg[q] = sk[lofs[q]];
    #pragma unroll
    for (int q = 0; q < 5; ++q) slab[0][lrr[q]][lcc[q]] = rg[q];
  }

  float outk[7];
  int cur = 0;
  #pragma unroll 1
  for (int kk = 0; kk < 7; ++kk) {
    if (kk < 6) {                          // issue next channel's loads early
      const float* sk = sb + (size_t)(kq * 7 + kk + 1) * 128 * 128;
      #pragma unroll
      for (int q = 0; q < 5; ++q) rg[q] = sk[lofs[q]];
    }
    __syncthreads();                       // slab[cur] writes visible
    float a = 0.f;
    #pragma unroll
    for (int ay = 0; ay < 4; ++ay) {
      int rel = 2 * oyl + ay;
      float rsum = 0.f;
      #pragma unroll
      for (int ax = 0; ax < 4; ++ax) rsum = fmaf(wx[ax], slab[cur][rel][tx[ax]], rsum);
      a = fmaf(wy[ay], rsum, a);
    }
    outk[kk] = a;
    if (kk < 6) {
      #pragma unroll
      for (int q = 0; q < 5; ++q) slab[cur ^ 1][lrr[q]][lcc[q]] = rg[q];
    }
    cur ^= 1;
  }

  _Float16 hv[7];
  #pragma unroll
  for (int kk = 0; kk < 7; ++kk) hv[kk] = (_Float16)outk[kk];
  char* rowp = (char*)(segh + (size_t)idx * ROWH);
  const _Float16 hz = (_Float16)0.f;
  if (kq == 0) {         // halves 0..6 -> bytes 0..13
    *(unsigned long long*)(rowp + 0)  = pk4(hv[0], hv[1], hv[2], hv[3]);
    *(unsigned int*)      (rowp + 8)  = pk2(hv[4], hv[5]);
    *(unsigned short*)    (rowp + 12) = h2u(hv[6]);
  } else if (kq == 1) {  // halves 7..13 -> bytes 14..27
    *(unsigned short*)    (rowp + 14) = h2u(hv[0]);
    *(unsigned long long*)(rowp + 16) = pk4(hv[1], hv[2], hv[3], hv[4]);
    *(unsigned int*)      (rowp + 24) = pk2(hv[5], hv[6]);
  } else {               // halves 14..20 + zero pad 21..31 -> bytes 28..63
    *(unsigned int*)      (rowp + 28) = pk2(hv[0], hv[1]);
    *(unsigned long long*)(rowp + 32) = pk4(hv[2], hv[3], hv[4], hv[5]);
    *(unsigned long long*)(rowp + 40) = pk4(hv[6], hz, hz, hz);
    *(unsigned long long*)(rowp + 48) = 0ull;
    *(unsigned long long*)(rowp + 56) = 0ull;
  }
}

// Block = (n, I, J) supertile pair (J>=I), 256 rows each side. B chunk staged in
// LDS (granule-SoA, conflict-free ds_read_b128); 4 waves x 4 i-tiles x 16 j-tiles.
__global__ void __launch_bounds__(256) crf_mfma(const _Float16* __restrict__ distA,
                                                const _Float16* __restrict__ distB,
                                                const _Float16* __restrict__ segh,
                                                double* __restrict__ acc,
                                                unsigned* __restrict__ ctr,
                                                float* __restrict__ out) {
  __shared__ char lds[32768];              // [2 arrays][4 granules][256 rows][16B]
  int bid = blockIdx.x;
  int n = bid / ITEMS_PER_IMG;
  int rem = bid % ITEMS_PER_IMG;
  int I = 0;
  while (rem >= NT - I) { rem -= NT - I; ++I; }
  int J = I + rem;

  int tid = threadIdx.x;
  int lane = tid & 63, wid = tid >> 6;
  int r = lane & 15, g4 = lane >> 4;

  const char* dA = (const char*)(distA + (size_t)n * NP * ROWH);
  const char* dB = (const char*)(distB + (size_t)n * NP * ROWH);
  const char* sg = (const char*)(segh  + (size_t)n * NP * ROWH);

  // stage B chunk J: global row-major -> LDS granule-SoA
  {
    const char* srcBd = dB + (size_t)J * 256 * 64;
    const char* srcBs = sg + (size_t)J * 256 * 64;
    #pragma unroll
    for (int q = 0; q < 4; ++q) {
      float4 vd = *(const float4*)(srcBd + tid * 64 + q * 16);
      float4 vs = *(const float4*)(srcBs + tid * 64 + q * 16);
      *(float4*)(lds + q * 4096 + tid * 16) = vd;
      *(float4*)(lds + 16384 + q * 4096 + tid * 16) = vs;
    }
  }

  // A fragments: this wave's 4 i-tiles (global; L2-resident, reused 16x)
  half8 Ad[4], As[4];
  #pragma unroll
  for (int m = 0; m < 4; ++m) {
    size_t aoff = (size_t)(I * 256 + (wid * 4 + m) * 16 + r) * 64 + g4 * 16;
    Ad[m] = *(const half8*)(dA + aoff);
    As[m] = *(const half8*)(sg + aoff);
  }
  __syncthreads();

  f32x4 zero = {0.f, 0.f, 0.f, 0.f};
  float sm0 = 0.f, sm1 = 0.f, sm2 = 0.f, sm3 = 0.f;
  float sum;

  if (J > I) {                             // all tiles weight 2
    #pragma unroll 4
    for (int jt = 0; jt < 16; ++jt) {
      const char* bp = lds + (size_t)g4 * 4096 + (jt * 16 + r) * 16;
      half8 Bd = *(const half8*)bp;
      half8 Bs = *(const half8*)(bp + 16384);
      #pragma unroll
      for (int m = 0; m < 4; ++m) {
        f32x4 ad  = __builtin_amdgcn_mfma_f32_16x16x32_f16(Ad[m], Bd, zero, 0, 0, 0);
        f32x4 as_ = __builtin_amdgcn_mfma_f32_16x16x32_f16(As[m], Bs, zero, 0, 0, 0);
        float t0 = fmaf(__builtin_amdgcn_exp2f(ad[0]), as_[0],
                   fmaf(__builtin_amdgcn_exp2f(ad[1]), as_[1], 0.f));
        float t1 = fmaf(__builtin_amdgcn_exp2f(ad[2]), as_[2],
                   fmaf(__builtin_amdgcn_exp2f(ad[3]), as_[3], 0.f));
        float t = t0 + t1;
        if (m == 0) sm0 += t; else if (m == 1) sm1 += t;
        else if (m == 2) sm2 += t; else sm3 += t;
      }
    }
    sum = 2.f * (sm0 + sm1 + sm2 + sm3);
  } else {                                 // diagonal: per-tile weight {0,1,2}
    #pragma unroll 2
    for (int jt = 0; jt < 16; ++jt) {
      int jta = I * 16 + jt;
      const char* bp = lds + (size_t)g4 * 4096 + (jt * 16 + r) * 16;
      half8 Bd = *(const half8*)bp;
      half8 Bs = *(const half8*)(bp + 16384);
      #pragma unroll
      for (int m = 0; m < 4; ++m) {
        int it = I * 16 + wid * 4 + m;
        if (jta >= it) {                   // wave-uniform skip of zero-weight tiles
          float s = (jta > it) ? 2.f : 1.f;
          f32x4 ad  = __builtin_amdgcn_mfma_f32_16x16x32_f16(Ad[m], Bd, zero, 0, 0, 0);
          f32x4 as_ = __builtin_amdgcn_mfma_f32_16x16x32_f16(As[m], Bs, zero, 0, 0, 0);
          float t0 = fmaf(__builtin_amdgcn_exp2f(ad[0]), as_[0],
                     fmaf(__builtin_amdgcn_exp2f(ad[1]), as_[1], 0.f));
          float t1 = fmaf(__builtin_amdgcn_exp2f(ad[2]), as_[2],
                     fmaf(__builtin_amdgcn_exp2f(ad[3]), as_[3], 0.f));
          float t = s * (t0 + t1);
          if (m == 0) sm0 += t; else if (m == 1) sm1 += t;
          else if (m == 2) sm2 += t; else sm3 += t;
        }
      }
    }
    sum = sm0 + sm1 + sm2 + sm3;
  }

  // block reduction (reuse staging LDS), device accumulate, last block writes out
  #pragma unroll
  for (int off = 32; off > 0; off >>= 1) sum += __shfl_down(sum, off);
  __syncthreads();                         // all LDS B-reads done
  float* red = (float*)lds;
  if (lane == 0) red[wid] = sum;
  __syncthreads();
  if (tid == 0) {
    float b = red[0] + red[1] + red[2] + red[3];
    atomicAdd(acc, (double)b);
    __threadfence();
    unsigned old = atomicAdd(ctr, 1u);
    if (old == (unsigned)(gridDim.x - 1)) {
      __threadfence();
      double s = *(volatile double*)acc;
      out[0] = (float)(s * (-1e-8 / 8.0));  // WEIGHT * (-sum/N)
    }
  }
}

extern "C" void kernel_launch(void* const* d_in, const int* in_sizes, int n_in,
                              void* d_out, int out_size, void* d_ws, size_t ws_size,
                              hipStream_t stream) {
  const float* images = (const float*)d_in[0];   // [8,3,64,64]
  const float* segs   = (const float*)d_in[1];   // [8,21,128,128]
  float* out  = (float*)d_out;
  double* acc = (double*)d_ws;
  unsigned* ctr = (unsigned*)((char*)d_ws + 8);
  _Float16* distA = (_Float16*)((char*)d_ws + 256);              // 2 MB
  _Float16* distB = distA + (size_t)NIMG * NP * ROWH;            // 2 MB
  _Float16* segh  = distB + (size_t)NIMG * NP * ROWH;            // 2 MB

  hipLaunchKernelGGL(prep_kernel, dim3(NIMG * 16 * 3), dim3(256), 0, stream,
                     images, segs, distA, distB, segh, acc, ctr);
  hipLaunchKernelGGL(crf_mfma, dim3(CRF_BLOCKS), dim3(256), 0, stream,
                     distA, distB, segh, acc, ctr, out);
}